// Round 1
// baseline (629.573 us; speedup 1.0000x reference)
//
#include <hip/hip_runtime.h>
#include <cstdint>
#include <cstddef>

#define T_TOK 2048
#define HID   2048
#define INTER 1408
#define NEXP  8
#define NPAIR 6144   /* 2*T routed + T shared */
#define LDST  40     /* LDS row stride in bf16 elems (80B, 16B-aligned) */

typedef __bf16 bf16x8 __attribute__((ext_vector_type(8)));
typedef float  floatx4 __attribute__((ext_vector_type(4)));

// ---- workspace layout (bytes) ----
static const size_t XB_OFF   = 0;                                   // bf16 x  [T,H]
static const size_t HM_OFF   = XB_OFF + (size_t)T_TOK * HID * 2;    // bf16 hmid [NPAIR, INTER]
static const size_t TOK_OFF  = HM_OFF + (size_t)NPAIR * INTER * 2;  // int  tok [NPAIR]
static const size_t WGT_OFF  = TOK_OFF + (size_t)NPAIR * 4;         // f32  wgt [NPAIR]
static const size_t TE_OFF   = WGT_OFF + (size_t)NPAIR * 4;         // int  top2 expert ids [T,2]
static const size_t TW_OFF   = TE_OFF + (size_t)T_TOK * 2 * 4;      // f32  top2 weights [T,2]
static const size_t CTRL_OFF = TW_OFF + (size_t)T_TOK * 2 * 4;      // int  counts[16] offsets[16] fill[16]

static __device__ __forceinline__ unsigned short f2bf(float f) {
    unsigned u = __float_as_uint(f);
    u += 0x7fffu + ((u >> 16) & 1u);          // round-to-nearest-even
    return (unsigned short)(u >> 16);
}
static __device__ __forceinline__ unsigned pk2(float a, float b) {
    return (unsigned)f2bf(a) | ((unsigned)f2bf(b) << 16);
}

// ---------------- x -> bf16 ----------------
__global__ __launch_bounds__(256) void k_cvt_x(const float* __restrict__ x,
                                               unsigned short* __restrict__ xb) {
    int gid = blockIdx.x * 256 + threadIdx.x;          // 8 elems each
    const float4* src = (const float4*)x;
    float4 a = src[gid * 2], b = src[gid * 2 + 1];
    uint4 o;
    o.x = pk2(a.x, a.y); o.y = pk2(a.z, a.w);
    o.z = pk2(b.x, b.y); o.w = pk2(b.z, b.w);
    ((uint4*)xb)[gid] = o;
}

// ---------------- router (fp32 exact) ----------------
__global__ __launch_bounds__(256) void k_router(const float* __restrict__ x,
                                                const float* __restrict__ rw,
                                                int* __restrict__ te, float* __restrict__ tw,
                                                int* __restrict__ counts) {
    int wave = threadIdx.x >> 6, lane = threadIdx.x & 63;
    int t = blockIdx.x * 4 + wave;
    const float* xp = x + (size_t)t * HID;

    float acc[8];
#pragma unroll
    for (int e = 0; e < 8; ++e) acc[e] = 0.f;
    for (int i = lane; i < HID; i += 64) {
        float xv = xp[i];
#pragma unroll
        for (int e = 0; e < 8; ++e) acc[e] = fmaf(xv, rw[e * HID + i], acc[e]);
    }
#pragma unroll
    for (int e = 0; e < 8; ++e) {
        float v = acc[e];
        for (int s = 32; s; s >>= 1) v += __shfl_xor(v, s, 64);
        acc[e] = v;
    }
    // softmax (max-shifted) — division cancels in renorm, use raw exps
    float mx = acc[0];
#pragma unroll
    for (int e = 1; e < 8; ++e) mx = fmaxf(mx, acc[e]);
    float p[8];
#pragma unroll
    for (int e = 0; e < 8; ++e) p[e] = __expf(acc[e] - mx);
    int i1 = 0; float v1 = p[0];
#pragma unroll
    for (int e = 1; e < 8; ++e) if (p[e] > v1) { v1 = p[e]; i1 = e; }
    int i2 = -1; float v2 = -1.f;
#pragma unroll
    for (int e = 0; e < 8; ++e) if (e != i1 && p[e] > v2) { v2 = p[e]; i2 = e; }
    float inv = 1.f / (v1 + v2);
    if (lane == 0) {
        te[2 * t] = i1;     tw[2 * t] = v1 * inv;
        te[2 * t + 1] = i2; tw[2 * t + 1] = v2 * inv;
        atomicAdd(&counts[i1], 1);
        atomicAdd(&counts[i2], 1);
    }
}

// ---------------- offsets (prefix over 8 counts) ----------------
__global__ void k_offsets(int* __restrict__ ctrl) {
    if (threadIdx.x == 0) {
        int s = 0;
        for (int e = 0; e < 8; ++e) { ctrl[16 + e] = s; s += ctrl[e]; }
        ctrl[16 + 8] = s;      // == 2*T
        ctrl[8] = T_TOK;       // shared expert count
    }
}

// ---------------- scatter pair lists ----------------
__global__ __launch_bounds__(256) void k_scatter(const int* __restrict__ te,
                                                 const float* __restrict__ tw,
                                                 const int* __restrict__ offsets,
                                                 int* __restrict__ fill,
                                                 int* __restrict__ tok, float* __restrict__ wgt) {
    int t = blockIdx.x * 256 + threadIdx.x;
    if (t >= T_TOK) return;
#pragma unroll
    for (int k = 0; k < 2; ++k) {
        int e = te[2 * t + k];
        int slot = atomicAdd(&fill[e], 1);
        int pp = offsets[e] + slot;
        tok[pp] = t; wgt[pp] = tw[2 * t + k];
    }
    tok[2 * T_TOK + t] = t; wgt[2 * T_TOK + t] = 1.0f;   // shared expert region
}

// ---------------- GEMM1: hmid = silu(x@gateT) * (x@upT), gathered rows ----------------
// tile: BM=128, BN=64 (both gate & up), BK=32. 256 thr / 4 waves; wave w -> rows w*32..+31.
__global__ __launch_bounds__(256) void k_gemm1(const unsigned short* __restrict__ xb,
                                               const float* __restrict__ gate_w,
                                               const float* __restrict__ up_w,
                                               const float* __restrict__ sgate,
                                               const float* __restrict__ sup,
                                               const int* __restrict__ tok,
                                               const int* __restrict__ ctrl,
                                               unsigned short* __restrict__ hmid) {
    int e = blockIdx.z;
    int cnt = ctrl[e];
    int m0 = blockIdx.y * 128;
    if (m0 >= cnt) return;
    int off = ctrl[16 + e];
    int i0 = blockIdx.x * 64;
    const float* gw = (e < 8) ? gate_w + (size_t)e * INTER * HID : sgate;
    const float* uw = (e < 8) ? up_w + (size_t)e * INTER * HID : sup;

    __shared__ __align__(16) unsigned short As[128 * LDST];
    __shared__ __align__(16) unsigned short Bg[64 * LDST];
    __shared__ __align__(16) unsigned short Bu[64 * LDST];

    int tid = threadIdx.x;
    int lane = tid & 63, wave = tid >> 6;
    int ar = tid >> 1, ac = (tid & 1) * 16;
    int ap = off + m0 + ar; if (ap > NPAIR - 1) ap = NPAIR - 1;
    const unsigned short* asrc = xb + (size_t)tok[ap] * HID + ac;
    int br = tid >> 2, bc = (tid & 3) * 8;
    const float* gsrc = gw + (size_t)(i0 + br) * HID + bc;
    const float* usrc = uw + (size_t)(i0 + br) * HID + bc;

    floatx4 accg[2][4], accu[2][4];
#pragma unroll
    for (int mi = 0; mi < 2; ++mi)
#pragma unroll
        for (int ni = 0; ni < 4; ++ni) {
            accg[mi][ni] = (floatx4){0.f, 0.f, 0.f, 0.f};
            accu[mi][ni] = (floatx4){0.f, 0.f, 0.f, 0.f};
        }

    int wm = wave * 32;
    int mrow = lane & 15, kq = (lane >> 4) * 8;

    for (int kt = 0; kt < HID / 32; ++kt) {
        int h0 = kt * 32;
        uint4 av0 = *(const uint4*)(asrc + h0);
        uint4 av1 = *(const uint4*)(asrc + h0 + 8);
        float4 g0 = *(const float4*)(gsrc + h0);
        float4 g1 = *(const float4*)(gsrc + h0 + 4);
        float4 u0 = *(const float4*)(usrc + h0);
        float4 u1 = *(const float4*)(usrc + h0 + 4);
        __syncthreads();
        *(uint4*)&As[ar * LDST + ac] = av0;
        *(uint4*)&As[ar * LDST + ac + 8] = av1;
        uint4 bg; bg.x = pk2(g0.x, g0.y); bg.y = pk2(g0.z, g0.w);
        bg.z = pk2(g1.x, g1.y); bg.w = pk2(g1.z, g1.w);
        *(uint4*)&Bg[br * LDST + bc] = bg;
        uint4 bu; bu.x = pk2(u0.x, u0.y); bu.y = pk2(u0.z, u0.w);
        bu.z = pk2(u1.x, u1.y); bu.w = pk2(u1.z, u1.w);
        *(uint4*)&Bu[br * LDST + bc] = bu;
        __syncthreads();

        bf16x8 af[2];
#pragma unroll
        for (int mi = 0; mi < 2; ++mi)
            af[mi] = *(const bf16x8*)&As[(wm + mi * 16 + mrow) * LDST + kq];
#pragma unroll
        for (int ni = 0; ni < 4; ++ni) {
            bf16x8 bgv = *(const bf16x8*)&Bg[(ni * 16 + mrow) * LDST + kq];
            bf16x8 buv = *(const bf16x8*)&Bu[(ni * 16 + mrow) * LDST + kq];
#pragma unroll
            for (int mi = 0; mi < 2; ++mi) {
                accg[mi][ni] = __builtin_amdgcn_mfma_f32_16x16x32_bf16(af[mi], bgv, accg[mi][ni], 0, 0, 0);
                accu[mi][ni] = __builtin_amdgcn_mfma_f32_16x16x32_bf16(af[mi], buv, accu[mi][ni], 0, 0, 0);
            }
        }
    }

    int quad = lane >> 4, col = lane & 15;
#pragma unroll
    for (int mi = 0; mi < 2; ++mi)
#pragma unroll
        for (int ni = 0; ni < 4; ++ni)
#pragma unroll
            for (int r = 0; r < 4; ++r) {
                int row = m0 + wm + mi * 16 + quad * 4 + r;
                if (row < cnt) {
                    float g = accg[mi][ni][r], u = accu[mi][ni][r];
                    float s = g / (1.f + __expf(-g));
                    hmid[(size_t)(off + row) * INTER + i0 + ni * 16 + col] = f2bf(s * u);
                }
            }
}

// ---------------- GEMM2: out[tok] += w * (hmid @ downT) ----------------
__global__ __launch_bounds__(256) void k_gemm2(const unsigned short* __restrict__ hmid,
                                               const float* __restrict__ down_w,
                                               const float* __restrict__ sdown,
                                               const int* __restrict__ tok,
                                               const float* __restrict__ wgt,
                                               const int* __restrict__ ctrl,
                                               float* __restrict__ out) {
    int e = blockIdx.z;
    int cnt = ctrl[e];
    int m0 = blockIdx.y * 128;
    if (m0 >= cnt) return;
    int off = ctrl[16 + e];
    int n0 = blockIdx.x * 64;
    const float* dw = (e < 8) ? down_w + (size_t)e * HID * INTER : sdown;

    __shared__ __align__(16) unsigned short As[128 * LDST];
    __shared__ __align__(16) unsigned short Bd[64 * LDST];

    int tid = threadIdx.x;
    int lane = tid & 63, wave = tid >> 6;
    int ar = tid >> 1, ac = (tid & 1) * 16;
    int ap = off + m0 + ar; if (ap > NPAIR - 1) ap = NPAIR - 1;
    const unsigned short* asrc = hmid + (size_t)ap * INTER + ac;
    int br = tid >> 2, bc = (tid & 3) * 8;
    const float* bsrc = dw + (size_t)(n0 + br) * INTER + bc;

    floatx4 acc[2][4];
#pragma unroll
    for (int mi = 0; mi < 2; ++mi)
#pragma unroll
        for (int ni = 0; ni < 4; ++ni) acc[mi][ni] = (floatx4){0.f, 0.f, 0.f, 0.f};

    int wm = wave * 32;
    int mrow = lane & 15, kq = (lane >> 4) * 8;

    for (int kt = 0; kt < INTER / 32; ++kt) {
        int k0 = kt * 32;
        uint4 av0 = *(const uint4*)(asrc + k0);
        uint4 av1 = *(const uint4*)(asrc + k0 + 8);
        float4 b0 = *(const float4*)(bsrc + k0);
        float4 b1 = *(const float4*)(bsrc + k0 + 4);
        __syncthreads();
        *(uint4*)&As[ar * LDST + ac] = av0;
        *(uint4*)&As[ar * LDST + ac + 8] = av1;
        uint4 bd; bd.x = pk2(b0.x, b0.y); bd.y = pk2(b0.z, b0.w);
        bd.z = pk2(b1.x, b1.y); bd.w = pk2(b1.z, b1.w);
        *(uint4*)&Bd[br * LDST + bc] = bd;
        __syncthreads();

        bf16x8 af[2];
#pragma unroll
        for (int mi = 0; mi < 2; ++mi)
            af[mi] = *(const bf16x8*)&As[(wm + mi * 16 + mrow) * LDST + kq];
#pragma unroll
        for (int ni = 0; ni < 4; ++ni) {
            bf16x8 bv = *(const bf16x8*)&Bd[(ni * 16 + mrow) * LDST + kq];
#pragma unroll
            for (int mi = 0; mi < 2; ++mi)
                acc[mi][ni] = __builtin_amdgcn_mfma_f32_16x16x32_bf16(af[mi], bv, acc[mi][ni], 0, 0, 0);
        }
    }

    int quad = lane >> 4, col = lane & 15;
#pragma unroll
    for (int mi = 0; mi < 2; ++mi)
#pragma unroll
        for (int r = 0; r < 4; ++r) {
            int row = m0 + wm + mi * 16 + quad * 4 + r;
            if (row < cnt) {
                int p = off + row;
                int t = tok[p];
                float w = wgt[p];
#pragma unroll
                for (int ni = 0; ni < 4; ++ni)
                    atomicAdd(&out[(size_t)t * HID + n0 + ni * 16 + col], w * acc[mi][ni][r]);
            }
        }
}

extern "C" void kernel_launch(void* const* d_in, const int* in_sizes, int n_in,
                              void* d_out, int out_size, void* d_ws, size_t ws_size,
                              hipStream_t stream) {
    const float* x        = (const float*)d_in[0];
    const float* router_w = (const float*)d_in[1];
    const float* gate_w   = (const float*)d_in[2];
    const float* up_w     = (const float*)d_in[3];
    const float* down_w   = (const float*)d_in[4];
    const float* sgate    = (const float*)d_in[5];
    const float* sup      = (const float*)d_in[6];
    const float* sdown    = (const float*)d_in[7];
    float* out = (float*)d_out;

    char* ws = (char*)d_ws;
    unsigned short* xb   = (unsigned short*)(ws + XB_OFF);
    unsigned short* hmid = (unsigned short*)(ws + HM_OFF);
    int*   tok  = (int*)(ws + TOK_OFF);
    float* wgt  = (float*)(ws + WGT_OFF);
    int*   te   = (int*)(ws + TE_OFF);
    float* tw   = (float*)(ws + TW_OFF);
    int*   ctrl = (int*)(ws + CTRL_OFF);   // counts[16] | offsets[16] | fill[16]

    hipMemsetAsync(ctrl, 0, 48 * sizeof(int), stream);
    hipMemsetAsync(out, 0, (size_t)T_TOK * HID * sizeof(float), stream);

    k_cvt_x  <<<(T_TOK * HID) / 8 / 256, 256, 0, stream>>>(x, xb);
    k_router <<<T_TOK / 4, 256, 0, stream>>>(x, router_w, te, tw, ctrl);
    k_offsets<<<1, 64, 0, stream>>>(ctrl);
    k_scatter<<<T_TOK / 256, 256, 0, stream>>>(te, tw, ctrl + 16, ctrl + 32, tok, wgt);

    k_gemm1<<<dim3(INTER / 64, 16, 9), 256, 0, stream>>>(xb, gate_w, up_w, sgate, sup, tok, ctrl, hmid);
    k_gemm2<<<dim3(HID / 64, 16, 9), 256, 0, stream>>>(hmid, down_w, sdown, tok, wgt, ctrl, out);
}